// Round 2
// baseline (14379.300 us; speedup 1.0000x reference)
//
#include <hip/hip_runtime.h>
#include <cstddef>

#define HS 64
#define WS 64
#define CSN 128
#define CMN 64
#define BN 32
#define TN 256
#define HW (HS*WS)

__device__ __forceinline__ float silu_f(float v) { return v / (1.f + __expf(-v)); }

// ---------------- resize: 2x2 average pool (scale=2, f=0.5 exactly) ----------------
__global__ __launch_bounds__(256) void resize_kernel(const float* __restrict__ M, float* __restrict__ Ms) {
  unsigned idx = blockIdx.x * 256u + threadIdx.x;   // B*CM*HW = 8388608
  if (idx >= (unsigned)BN * CMN * HW) return;
  unsigned x = idx & 63u, y = (idx >> 6) & 63u, bc = idx >> 12;
  const float* p = M + ((size_t)bc * 128 + 2 * y) * 128 + 2 * x;
  Ms[idx] = 0.25f * (p[0] + p[1] + p[128] + p[129]);
}

__global__ __launch_bounds__(256) void copy_kernel(const float* __restrict__ src, float* __restrict__ dst, int n) {
  int i = blockIdx.x * 256 + threadIdx.x;
  if (i < n) dst[i] = src[i];
}

// ---------------- t_embed contribution to in_proj (per (b,oc)), includes bias ----------------
__global__ __launch_bounds__(256) void tctr_kernel(const float* __restrict__ w, const float* __restrict__ bias,
                                                   const float* __restrict__ te, float* __restrict__ tctr) {
  int i = blockIdx.x * 256 + threadIdx.x;  // B*CS = 4096
  if (i >= BN * CSN) return;
  int b = i >> 7, o = i & 127;
  float acc = bias[o];
  const float* wp = w + (size_t)o * 195 + 67;   // t channels are 67..194
  const float* t = te + b * 128;
  #pragma unroll 8
  for (int k = 0; k < 128; ++k) acc += wp[k] * t[k];
  tctr[i] = acc;
}

// ---------------- t_embed contribution to mlp layer1 (per (b,j)), includes b1 ----------------
__global__ __launch_bounds__(256) void tpart_kernel(const float* __restrict__ w1, const float* __restrict__ b1,
                                                    const float* __restrict__ te, float* __restrict__ tp) {
  int i = blockIdx.x * 256 + threadIdx.x;  // B*128
  if (i >= BN * 128) return;
  int b = i >> 7, j = i & 127;
  float acc = b1[j];
  #pragma unroll 8
  for (int k = 0; k < 128; ++k) acc += te[b * 128 + k] * w1[(size_t)(128 + k) * 128 + j];
  tp[i] = acc;
}

// ---------------- rasterize velocity field ----------------
__global__ __launch_bounds__(256) void raster_kernel(const float* __restrict__ x, float* __restrict__ P) {
  int b = blockIdx.y;
  int pix = blockIdx.x * 256 + threadIdx.x;     // 16 blocks x 256 = 4096 pixels
  __shared__ float spx[TN], spy[TN];
  {
    float xv = x[(b * TN + threadIdx.x) * 2];
    float yv = x[(b * TN + threadIdx.x) * 2 + 1];
    spx[threadIdx.x] = (xv + 1.f) * 0.5f * (WS - 1);
    spy[threadIdx.x] = (yv + 1.f) * 0.5f * (HS - 1);
  }
  __syncthreads();
  float fx = (float)(pix & 63), fy = (float)(pix >> 6);
  const float coef = -0.5f / (1.44f + 1e-8f);   // sigma^2 = 1.44
  float heat = 0.f, sx = 0.f, sy = 0.f, sw = 0.f;
  float prevx = 0.f, prevy = 0.f;
  for (int t = 0; t < TN; ++t) {
    float px = spx[t], py = spy[t];
    float ddx = px - fx, ddy = py - fy;
    float w = __expf(coef * (ddx * ddx + ddy * ddy));
    heat = fmaxf(heat, w);
    float vx = (t == 0) ? 0.f : px - prevx;
    float vy = (t == 0) ? 0.f : py - prevy;
    prevx = px; prevy = py;
    sx += w * vx; sy += w * vy; sw += w;
  }
  float inv = 1.f / fmaxf(sw, 1e-6f);
  P[((size_t)b * 3 + 0) * HW + pix] = heat;
  P[((size_t)b * 3 + 1) * HW + pix] = sx * inv;
  P[((size_t)b * 3 + 2) * HW + pix] = sy * inv;
}

// ---------------- in_proj 1x1 conv over concat[Ms(64), P(3), t(128 via tctr)] ----------------
__global__ __launch_bounds__(256) void in_proj_kernel(const float* __restrict__ Ms, const float* __restrict__ P,
                                                      const float* __restrict__ w, const float* __restrict__ tctr,
                                                      float* __restrict__ S) {
  int b = blockIdx.z;
  int oc0 = blockIdx.y * 4;
  int pix = blockIdx.x * 256 + threadIdx.x;
  float a0 = tctr[b * 128 + oc0 + 0];
  float a1 = tctr[b * 128 + oc0 + 1];
  float a2 = tctr[b * 128 + oc0 + 2];
  float a3 = tctr[b * 128 + oc0 + 3];
  const float* w0 = w + (size_t)(oc0 + 0) * 195;
  const float* w1p = w + (size_t)(oc0 + 1) * 195;
  const float* w2p = w + (size_t)(oc0 + 2) * 195;
  const float* w3p = w + (size_t)(oc0 + 3) * 195;
  const float* msp = Ms + (size_t)b * CMN * HW + pix;
  #pragma unroll 4
  for (int ic = 0; ic < 64; ++ic) {
    float v = msp[(size_t)ic * HW];
    a0 += w0[ic] * v; a1 += w1p[ic] * v; a2 += w2p[ic] * v; a3 += w3p[ic] * v;
  }
  const float* pp = P + (size_t)b * 3 * HW + pix;
  #pragma unroll
  for (int i = 0; i < 3; ++i) {
    float v = pp[(size_t)i * HW];
    a0 += w0[64 + i] * v; a1 += w1p[64 + i] * v; a2 += w2p[64 + i] * v; a3 += w3p[64 + i] * v;
  }
  float* sp = S + ((size_t)b * CSN + oc0) * HW + pix;
  sp[0] = a0; sp[HW] = a1; sp[2 * HW] = a2; sp[3 * HW] = a3;
}

// ---------------- out_proj 1x1 conv 128->128 ----------------
__global__ __launch_bounds__(256) void out_proj_kernel(const float* __restrict__ S, const float* __restrict__ w,
                                                       const float* __restrict__ bias, float* __restrict__ O) {
  int b = blockIdx.z;
  int oc0 = blockIdx.y * 4;
  int pix = blockIdx.x * 256 + threadIdx.x;
  float a0 = bias[oc0], a1 = bias[oc0 + 1], a2 = bias[oc0 + 2], a3 = bias[oc0 + 3];
  const float* w0 = w + (size_t)oc0 * 128;
  const float* sp = S + (size_t)b * CSN * HW + pix;
  #pragma unroll 4
  for (int ic = 0; ic < 128; ++ic) {
    float v = sp[(size_t)ic * HW];
    a0 += w0[ic] * v; a1 += w0[128 + ic] * v; a2 += w0[256 + ic] * v; a3 += w0[384 + ic] * v;
  }
  float* op = O + ((size_t)b * CSN + oc0) * HW + pix;
  op[0] = a0; op[HW] = a1; op[2 * HW] = a2; op[3 * HW] = a3;
}

// ---------------- conv3x3 128->128, SAME, direct with LDS staging ----------------
// block: 256 threads -> (b, rows y0..y0+1, all 64 x, all 128 oc); thread: 8 x positions x 8 oc
__global__ __launch_bounds__(256, 2) void conv3x3_kernel(const float* __restrict__ In, const float* __restrict__ W,
                                                         const float* __restrict__ Bias, float* __restrict__ Out) {
  const int b = blockIdx.y;
  const int y0 = blockIdx.x * 2;
  const int tid = threadIdx.x;
  const int ocg = tid & 15;        // 16 groups of 8 oc
  const int pg = tid >> 4;         // 16 pos groups of 8 x
  const int row = pg >> 3;         // 0/1
  const int x0 = (pg & 7) * 8;
  __shared__ float sIn[8][4][68];  // ic-chunk x 4 rows x (x=-1..64 stored at +1)
  __shared__ float sW[72][128];    // (ic*9+tap) x oc
  float acc[8][8];
  #pragma unroll
  for (int i = 0; i < 8; ++i)
    #pragma unroll
    for (int j = 0; j < 8; ++j) acc[i][j] = 0.f;

  for (int icc = 0; icc < 128; icc += 8) {
    __syncthreads();
    for (int i = tid; i < 8 * 4 * 66; i += 256) {
      int ic = i / 264, rem = i % 264;
      int r = rem / 66, xs = rem % 66;
      int yy = y0 - 1 + r, xx = xs - 1;
      float v = 0.f;
      if (yy >= 0 && yy < 64 && xx >= 0 && xx < 64)
        v = In[(((size_t)b * CSN + icc + ic) * 64 + yy) * 64 + xx];
      sIn[ic][r][xs] = v;
    }
    for (int i = tid; i < 72 * 128; i += 256) {
      int oc = i / 72, k = i % 72;
      sW[k][oc] = W[(size_t)oc * 1152 + icc * 9 + k];
    }
    __syncthreads();
    for (int ic = 0; ic < 8; ++ic) {
      #pragma unroll
      for (int dy = 0; dy < 3; ++dy) {
        float iv[10];
        #pragma unroll
        for (int t = 0; t < 10; ++t) iv[t] = sIn[ic][row + dy][x0 + t];
        #pragma unroll
        for (int dx = 0; dx < 3; ++dx) {
          const float* wp = &sW[ic * 9 + dy * 3 + dx][ocg * 8];
          float wv[8];
          #pragma unroll
          for (int j = 0; j < 8; ++j) wv[j] = wp[j];
          #pragma unroll
          for (int i = 0; i < 8; ++i)
            #pragma unroll
            for (int j = 0; j < 8; ++j)
              acc[i][j] += iv[i + dx] * wv[j];
        }
      }
    }
  }
  #pragma unroll
  for (int j = 0; j < 8; ++j) {
    int oc = ocg * 8 + j;
    float bj = Bias[oc];
    float* op = Out + (((size_t)b * CSN + oc) * 64 + y0 + row) * 64 + x0;
    #pragma unroll
    for (int i = 0; i < 8; ++i) op[i] = acc[i][j] + bj;
  }
}

// ---------------- GroupNorm stats: one block per (b,g), 16ch x 4096 contiguous ----------------
__global__ __launch_bounds__(256) void gn_stats_kernel(const float* __restrict__ X, float* __restrict__ stats) {
  int bg = blockIdx.x;  // b*8+g
  const float* p = X + (size_t)bg * 16 * HW;
  float s = 0.f, sq = 0.f;
  for (int i = threadIdx.x; i < 16 * HW; i += 256) { float v = p[i]; s += v; sq += v * v; }
  __shared__ float ss[256], s2[256];
  ss[threadIdx.x] = s; s2[threadIdx.x] = sq;
  __syncthreads();
  for (int off = 128; off > 0; off >>= 1) {
    if (threadIdx.x < off) { ss[threadIdx.x] += ss[threadIdx.x + off]; s2[threadIdx.x] += s2[threadIdx.x + off]; }
    __syncthreads();
  }
  if (threadIdx.x == 0) {
    const float invn = 1.f / (16.f * HW);
    float mu = ss[0] * invn;
    float var = s2[0] * invn - mu * mu;
    stats[bg * 2] = mu;
    stats[bg * 2 + 1] = rsqrtf(var + 1e-5f);
  }
}

__global__ __launch_bounds__(256) void gn1_silu_kernel(float* __restrict__ A, const float* __restrict__ stats,
                                                       const float* __restrict__ gamma, const float* __restrict__ beta) {
  unsigned idx = blockIdx.x * 256u + threadIdx.x;   // 16777216
  unsigned pc = idx >> 12;
  int c = pc & 127, b = pc >> 7;
  int bg = b * 8 + (c >> 4);
  float mu = stats[bg * 2], ri = stats[bg * 2 + 1];
  float v = A[idx];
  float y = (v - mu) * ri * gamma[c] + beta[c];
  A[idx] = silu_f(y);
}

__global__ __launch_bounds__(256) void gn2_add_silu_kernel(float* __restrict__ S, const float* __restrict__ Xc,
                                                           const float* __restrict__ stats, const float* __restrict__ gamma,
                                                           const float* __restrict__ beta) {
  unsigned idx = blockIdx.x * 256u + threadIdx.x;
  unsigned pc = idx >> 12;
  int c = pc & 127, b = pc >> 7;
  int bg = b * 8 + (c >> 4);
  float mu = stats[bg * 2], ri = stats[bg * 2 + 1];
  float v = Xc[idx];
  float y = (v - mu) * ri * gamma[c] + beta[c];
  float s = S[idx] + y;
  S[idx] = silu_f(s);
}

// ---------------- grid_sample: one block (128 ch) per token ----------------
__global__ __launch_bounds__(128) void gsample_kernel(const float* __restrict__ S2, const float* __restrict__ x,
                                                      float* __restrict__ rd) {
  int token = blockIdx.x;   // B*T
  int c = threadIdx.x;
  int b = token >> 8;
  float cx = x[token * 2], cy = x[token * 2 + 1];
  float fx = (cx + 1.f) * 32.f - 0.5f;   // ((cx+1)*W - 1)*0.5, W=64
  float fy = (cy + 1.f) * 32.f - 0.5f;
  float x0f = floorf(fx), y0f = floorf(fy);
  float wx = fx - x0f, wy = fy - y0f;
  const float* Sb = S2 + ((size_t)b * CSN + c) * HW;
  float acc = 0.f;
  #pragma unroll
  for (int cor = 0; cor < 4; ++cor) {
    float xi = x0f + (float)(cor & 1), yi = y0f + (float)(cor >> 1);
    float wgt = ((cor & 1) ? wx : 1.f - wx) * ((cor >> 1) ? wy : 1.f - wy);
    if (xi >= 0.f && xi <= 63.f && yi >= 0.f && yi <= 63.f)
      acc += Sb[(int)yi * 64 + (int)xi] * wgt;
  }
  rd[(size_t)token * CSN + c] = acc;
}

// ---------------- MLP fc (128->128) with silu; init is per-j bias or per-(b,j) table ----------------
__global__ __launch_bounds__(256) void mlp_fc_kernel(const float* __restrict__ in, const float* __restrict__ w,
                                                     const float* __restrict__ init, int initPerB,
                                                     float* __restrict__ out) {
  int tok0 = blockIdx.x * 2;
  int tid = threadIdx.x;
  __shared__ float sr[2][128];
  sr[tid >> 7][tid & 127] = in[(size_t)tok0 * 128 + tid];
  __syncthreads();
  int t = tid >> 7, j = tid & 127;
  int token = tok0 + t;
  int b = token >> 8;
  float acc = initPerB ? init[b * 128 + j] : init[j];
  #pragma unroll 8
  for (int k = 0; k < 128; ++k) acc += sr[t][k] * w[(size_t)k * 128 + j];
  out[(size_t)token * 128 + j] = silu_f(acc);
}

__global__ __launch_bounds__(256) void mlp3_update_kernel(const float* __restrict__ h2, const float* __restrict__ w3,
                                                          const float* __restrict__ b3, float* __restrict__ x) {
  int token = blockIdx.x * 256 + threadIdx.x;
  if (token >= BN * TN) return;
  float d0 = b3[0], d1 = b3[1];
  const float* h = h2 + (size_t)token * 128;
  #pragma unroll 8
  for (int k = 0; k < 128; ++k) { float hv = h[k]; d0 += hv * w3[k * 2]; d1 += hv * w3[k * 2 + 1]; }
  float nx = x[token * 2] + 0.2f * d0;
  float ny = x[token * 2 + 1] + 0.2f * d1;
  x[token * 2] = fminf(fmaxf(nx, -1.f), 1.f);
  x[token * 2 + 1] = fminf(fmaxf(ny, -1.f), 1.f);
}

extern "C" void kernel_launch(void* const* d_in, const int* in_sizes, int n_in,
                              void* d_out, int out_size, void* d_ws, size_t ws_size,
                              hipStream_t stream) {
  const float* M   = (const float*)d_in[0];
  const float* x0  = (const float*)d_in[1];
  const float* te  = (const float*)d_in[2];
  const float* ipw = (const float*)d_in[3];
  const float* ipb = (const float*)d_in[4];
  const float* c1w = (const float*)d_in[5];
  const float* c1b = (const float*)d_in[6];
  const float* g1w = (const float*)d_in[7];
  const float* g1b = (const float*)d_in[8];
  const float* c2w = (const float*)d_in[9];
  const float* c2b = (const float*)d_in[10];
  const float* g2w = (const float*)d_in[11];
  const float* g2b = (const float*)d_in[12];
  const float* ow  = (const float*)d_in[13];
  const float* ob  = (const float*)d_in[14];
  const float* w1  = (const float*)d_in[15];
  const float* b1  = (const float*)d_in[16];
  const float* w2  = (const float*)d_in[17];
  const float* b2  = (const float*)d_in[18];
  const float* w3  = (const float*)d_in[19];
  const float* b3  = (const float*)d_in[20];

  // workspace layout (floats); total ~236.5 MB
  float* ws    = (float*)d_ws;
  float* wx    = ws;                    // 16384 (current x state)
  float* Ms    = wx + 16384;            // 8388608
  float* P     = Ms + 8388608;          // 393216
  float* tctr  = P + 393216;            // 4096
  float* tpart = tctr + 4096;           // 4096
  float* stats = tpart + 4096;          // 512
  float* S     = stats + 512;           // 16777216
  float* A     = S + 16777216;          // 16777216
  float* Bb    = A + 16777216;          // 16777216
  float* rd    = Bb;                    // overlay: Bb free during tail
  float* h1    = Bb + 1048576;
  float* h2    = Bb + 2097152;

  copy_kernel<<<64, 256, 0, stream>>>(x0, wx, 16384);
  resize_kernel<<<32768, 256, 0, stream>>>(M, Ms);
  tctr_kernel<<<16, 256, 0, stream>>>(ipw, ipb, te, tctr);
  tpart_kernel<<<16, 256, 0, stream>>>(w1, b1, te, tpart);

  for (int r = 0; r < 3; ++r) {
    raster_kernel<<<dim3(16, 32), 256, 0, stream>>>(wx, P);
    in_proj_kernel<<<dim3(16, 32, 32), 256, 0, stream>>>(Ms, P, ipw, tctr, S);
    for (int i = 0; i < 3; ++i) {
      conv3x3_kernel<<<dim3(32, 32), 256, 0, stream>>>(S, c1w + (size_t)i * 147456, c1b + i * 128, A);
      gn_stats_kernel<<<256, 256, 0, stream>>>(A, stats);
      gn1_silu_kernel<<<65536, 256, 0, stream>>>(A, stats, g1w + i * 128, g1b + i * 128);
      conv3x3_kernel<<<dim3(32, 32), 256, 0, stream>>>(A, c2w + (size_t)i * 147456, c2b + i * 128, Bb);
      gn_stats_kernel<<<256, 256, 0, stream>>>(Bb, stats);
      gn2_add_silu_kernel<<<65536, 256, 0, stream>>>(S, Bb, stats, g2w + i * 128, g2b + i * 128);
    }
    out_proj_kernel<<<dim3(16, 32, 32), 256, 0, stream>>>(S, ow, ob, A);
    gsample_kernel<<<8192, 128, 0, stream>>>(A, wx, rd);
    mlp_fc_kernel<<<4096, 256, 0, stream>>>(rd, w1, tpart, 1, h1);
    mlp_fc_kernel<<<4096, 256, 0, stream>>>(h1, w2, b2, 0, h2);
    mlp3_update_kernel<<<32, 256, 0, stream>>>(h2, w3, b3, wx);
  }
  copy_kernel<<<64, 256, 0, stream>>>(wx, (float*)d_out, 16384);
}

// Round 5
// 5289.082 us; speedup vs baseline: 2.7187x; 2.7187x over previous
//
#include <hip/hip_runtime.h>
#include <cstddef>

#define HS 64
#define WS 64
#define CSN 128
#define CMN 64
#define BN 32
#define TN 256
#define HW (HS*WS)

typedef __attribute__((ext_vector_type(8))) short bf16x8;
typedef __attribute__((ext_vector_type(4))) float f32x4;

struct __attribute__((aligned(16))) U4 { unsigned x, y, z, w; };

__device__ __forceinline__ float silu_f(float v) { return v / (1.f + __expf(-v)); }

__device__ __forceinline__ unsigned short f2bf(float f) {
  unsigned u = __float_as_uint(f);
  unsigned r = (u + 0x7fffu + ((u >> 16) & 1u)) >> 16;
  return (unsigned short)r;
}

// ---------------- resize: 2x2 average pool (scale=2, f=0.5 exactly) ----------------
__global__ __launch_bounds__(256) void resize_kernel(const float* __restrict__ M, float* __restrict__ Ms) {
  unsigned idx = blockIdx.x * 256u + threadIdx.x;   // B*CM*HW = 8388608
  if (idx >= (unsigned)BN * CMN * HW) return;
  unsigned x = idx & 63u, y = (idx >> 6) & 63u, bc = idx >> 12;
  const float* p = M + ((size_t)bc * 128 + 2 * y) * 128 + 2 * x;
  Ms[idx] = 0.25f * (p[0] + p[1] + p[128] + p[129]);
}

__global__ __launch_bounds__(256) void copy_kernel(const float* __restrict__ src, float* __restrict__ dst, int n) {
  int i = blockIdx.x * 256 + threadIdx.x;
  if (i < n) dst[i] = src[i];
}

// ---------------- weight prep: W[oc][ic][3][3] fp32 -> Wb[(tap*4+chunk)*128+oc][32] bf16 ----------------
__global__ __launch_bounds__(256) void wprep_kernel(const float* __restrict__ Wsrc, unsigned short* __restrict__ Wdst) {
  int idx = blockIdx.x * 256 + threadIdx.x;  // 147456
  if (idx >= 147456) return;
  int icp = idx & 31;
  int oc = (idx >> 5) & 127;
  int tc = idx >> 12;        // tap*4 + chunk, 0..35
  int t = tc >> 2, cch = tc & 3;
  float f = Wsrc[(size_t)oc * 1152 + (size_t)(cch * 32 + icp) * 9 + t];
  Wdst[idx] = f2bf(f);
}

// ---------------- t_embed contribution to in_proj (per (b,oc)), includes bias ----------------
__global__ __launch_bounds__(256) void tctr_kernel(const float* __restrict__ w, const float* __restrict__ bias,
                                                   const float* __restrict__ te, float* __restrict__ tctr) {
  int i = blockIdx.x * 256 + threadIdx.x;  // B*CS = 4096
  if (i >= BN * CSN) return;
  int b = i >> 7, o = i & 127;
  float acc = bias[o];
  const float* wp = w + (size_t)o * 195 + 67;   // t channels are 67..194
  const float* t = te + b * 128;
  #pragma unroll 8
  for (int k = 0; k < 128; ++k) acc += wp[k] * t[k];
  tctr[i] = acc;
}

// ---------------- t_embed contribution to mlp layer1 (per (b,j)), includes b1 ----------------
__global__ __launch_bounds__(256) void tpart_kernel(const float* __restrict__ w1, const float* __restrict__ b1,
                                                    const float* __restrict__ te, float* __restrict__ tp) {
  int i = blockIdx.x * 256 + threadIdx.x;  // B*128
  if (i >= BN * 128) return;
  int b = i >> 7, j = i & 127;
  float acc = b1[j];
  #pragma unroll 8
  for (int k = 0; k < 128; ++k) acc += te[b * 128 + k] * w1[(size_t)(128 + k) * 128 + j];
  tp[i] = acc;
}

// ---------------- rasterize velocity field ----------------
__global__ __launch_bounds__(256) void raster_kernel(const float* __restrict__ x, float* __restrict__ P) {
  int b = blockIdx.y;
  int pix = blockIdx.x * 256 + threadIdx.x;     // 16 blocks x 256 = 4096 pixels
  __shared__ float spx[TN], spy[TN];
  {
    float xv = x[(b * TN + threadIdx.x) * 2];
    float yv = x[(b * TN + threadIdx.x) * 2 + 1];
    spx[threadIdx.x] = (xv + 1.f) * 0.5f * (WS - 1);
    spy[threadIdx.x] = (yv + 1.f) * 0.5f * (HS - 1);
  }
  __syncthreads();
  float fx = (float)(pix & 63), fy = (float)(pix >> 6);
  const float coef = -0.5f / (1.44f + 1e-8f);   // sigma^2 = 1.44
  float heat = 0.f, sx = 0.f, sy = 0.f, sw = 0.f;
  float prevx = 0.f, prevy = 0.f;
  for (int t = 0; t < TN; ++t) {
    float px = spx[t], py = spy[t];
    float ddx = px - fx, ddy = py - fy;
    float w = __expf(coef * (ddx * ddx + ddy * ddy));
    heat = fmaxf(heat, w);
    float vx = (t == 0) ? 0.f : px - prevx;
    float vy = (t == 0) ? 0.f : py - prevy;
    prevx = px; prevy = py;
    sx += w * vx; sy += w * vy; sw += w;
  }
  float inv = 1.f / fmaxf(sw, 1e-6f);
  P[((size_t)b * 3 + 0) * HW + pix] = heat;
  P[((size_t)b * 3 + 1) * HW + pix] = sx * inv;
  P[((size_t)b * 3 + 2) * HW + pix] = sy * inv;
}

// ---------------- in_proj 1x1 conv over concat[Ms(64), P(3), t(128 via tctr)] ----------------
__global__ __launch_bounds__(256) void in_proj_kernel(const float* __restrict__ Ms, const float* __restrict__ P,
                                                      const float* __restrict__ w, const float* __restrict__ tctr,
                                                      float* __restrict__ S) {
  int b = blockIdx.z;
  int oc0 = blockIdx.y * 4;
  int pix = blockIdx.x * 256 + threadIdx.x;
  float a0 = tctr[b * 128 + oc0 + 0];
  float a1 = tctr[b * 128 + oc0 + 1];
  float a2 = tctr[b * 128 + oc0 + 2];
  float a3 = tctr[b * 128 + oc0 + 3];
  const float* w0 = w + (size_t)(oc0 + 0) * 195;
  const float* w1p = w + (size_t)(oc0 + 1) * 195;
  const float* w2p = w + (size_t)(oc0 + 2) * 195;
  const float* w3p = w + (size_t)(oc0 + 3) * 195;
  const float* msp = Ms + (size_t)b * CMN * HW + pix;
  #pragma unroll 4
  for (int ic = 0; ic < 64; ++ic) {
    float v = msp[(size_t)ic * HW];
    a0 += w0[ic] * v; a1 += w1p[ic] * v; a2 += w2p[ic] * v; a3 += w3p[ic] * v;
  }
  const float* pp = P + (size_t)b * 3 * HW + pix;
  #pragma unroll
  for (int i = 0; i < 3; ++i) {
    float v = pp[(size_t)i * HW];
    a0 += w0[64 + i] * v; a1 += w1p[64 + i] * v; a2 += w2p[64 + i] * v; a3 += w3p[64 + i] * v;
  }
  float* sp = S + ((size_t)b * CSN + oc0) * HW + pix;
  sp[0] = a0; sp[HW] = a1; sp[2 * HW] = a2; sp[3 * HW] = a3;
}

// ---------------- out_proj 1x1 conv 128->128 ----------------
__global__ __launch_bounds__(256) void out_proj_kernel(const float* __restrict__ S, const float* __restrict__ w,
                                                       const float* __restrict__ bias, float* __restrict__ O) {
  int b = blockIdx.z;
  int oc0 = blockIdx.y * 4;
  int pix = blockIdx.x * 256 + threadIdx.x;
  float a0 = bias[oc0], a1 = bias[oc0 + 1], a2 = bias[oc0 + 2], a3 = bias[oc0 + 3];
  const float* w0 = w + (size_t)oc0 * 128;
  const float* sp = S + (size_t)b * CSN * HW + pix;
  #pragma unroll 4
  for (int ic = 0; ic < 128; ++ic) {
    float v = sp[(size_t)ic * HW];
    a0 += w0[ic] * v; a1 += w0[128 + ic] * v; a2 += w0[256 + ic] * v; a3 += w0[384 + ic] * v;
  }
  float* op = O + ((size_t)b * CSN + oc0) * HW + pix;
  op[0] = a0; op[HW] = a1; op[2 * HW] = a2; op[3 * HW] = a3;
}

// ================= conv3x3 via bf16 MFMA implicit GEMM =================
// M = oc(128), N = pixels(512 = 8 rows x 64), K = 9 taps x 128 ic (tap-major, 32-chunks).
// Block: 512 thr / 8 waves; wave = 64 oc x 128 px (M_rep=4, N_rep=8).
// A (weights) from global bf16 table; B (input patches) from swizzled LDS, double-buffered.
// LDS tile: [10 rows][66 xs][32 ic] bf16 as uint4 subblocks, sub ^= (xs>>1)&3.

__device__ __forceinline__ void stage_load(const float* __restrict__ In, int b, int cc, int y0, int sbid,
                                           float v[8]) {
  int r = sbid / 264;
  int t = sbid - r * 264;
  int xs = t >> 2, sb = t & 3;
  int y = y0 - 1 + r, x = xs - 1;
  bool ok = (y >= 0) && (y < 64) && (x >= 0) && (x < 64);
  const float* p = In + ((size_t)(b * 128 + cc * 32 + sb * 8)) * 4096 + y * 64 + x;
  #pragma unroll
  for (int j = 0; j < 8; ++j) v[j] = ok ? p[(size_t)j * 4096] : 0.f;
}

__device__ __forceinline__ void stage_write(U4* __restrict__ buf, int sbid, const float v[8]) {
  int r = sbid / 264;
  int t = sbid - r * 264;
  int xs = t >> 2, sb = t & 3;
  int slot = (r * 66 + xs) * 4 + (sb ^ ((xs >> 1) & 3));
  U4 q;
  q.x = (unsigned)f2bf(v[0]) | ((unsigned)f2bf(v[1]) << 16);
  q.y = (unsigned)f2bf(v[2]) | ((unsigned)f2bf(v[3]) << 16);
  q.z = (unsigned)f2bf(v[4]) | ((unsigned)f2bf(v[5]) << 16);
  q.w = (unsigned)f2bf(v[6]) | ((unsigned)f2bf(v[7]) << 16);
  buf[slot] = q;
}

template<int T0, int T1>
__device__ __forceinline__ void do_taps(const U4* __restrict__ cbuf, const unsigned short* __restrict__ Wb,
                                        int c, int oc0, int row0, int l15, int k8, f32x4 acc[4][8]) {
  #pragma unroll
  for (int t = T0; t < T1; ++t) {
    const int ky = t / 3, kx = t % 3;
    bf16x8 a[4];
    #pragma unroll
    for (int mf = 0; mf < 4; ++mf) {
      int oc = oc0 + mf * 16 + l15;
      const U4* ap = (const U4*)(Wb + (((size_t)(t * 4 + c) * 128 + oc) * 32 + k8 * 8));
      a[mf] = __builtin_bit_cast(bf16x8, *ap);
    }
    #pragma unroll
    for (int nf = 0; nf < 8; ++nf) {
      int r = row0 + (nf >> 2) + ky;
      int xs = (nf & 3) * 16 + l15 + kx;
      int slot = (r * 66 + xs) * 4 + (k8 ^ ((xs >> 1) & 3));
      bf16x8 bv = __builtin_bit_cast(bf16x8, cbuf[slot]);
      #pragma unroll
      for (int mf = 0; mf < 4; ++mf)
        acc[mf][nf] = __builtin_amdgcn_mfma_f32_16x16x32_bf16(a[mf], bv, acc[mf][nf], 0, 0, 0);
    }
  }
}

__global__ __launch_bounds__(512, 2) void conv3x3_mfma_kernel(const float* __restrict__ In,
                                                              const unsigned short* __restrict__ Wb,
                                                              const float* __restrict__ Bias,
                                                              float* __restrict__ Out) {
  const int b = blockIdx.y;
  const int y0 = blockIdx.x * 8;
  const int tid = threadIdx.x;
  const int l = tid & 63;
  const int w = tid >> 6;
  const int oc0 = (w & 1) * 64;
  const int row0 = (w >> 1) * 2;
  const int l15 = l & 15;
  const int k8 = l >> 4;

  __shared__ U4 lbuf[2][2640];   // 2 x 10 x 66 x 4 subblocks (84.5 KB)

  f32x4 acc[4][8];
  #pragma unroll
  for (int mf = 0; mf < 4; ++mf)
    #pragma unroll
    for (int nf = 0; nf < 8; ++nf)
      acc[mf][nf] = (f32x4){0.f, 0.f, 0.f, 0.f};

  // prologue: stage chunk 0 into buf 0
  {
    float v[8];
    #pragma unroll 1
    for (int rr = 0; rr < 5; ++rr) {
      stage_load(In, b, 0, y0, tid + rr * 512, v);
      stage_write(lbuf[0], tid + rr * 512, v);
    }
    if (tid < 80) {
      stage_load(In, b, 0, y0, tid + 2560, v);
      stage_write(lbuf[0], tid + 2560, v);
    }
  }
  __syncthreads();

  for (int c = 0; c < 4; ++c) {
    const U4* cbuf = lbuf[c & 1];
    U4* nbuf = lbuf[(c & 1) ^ 1];
    const bool st = (c < 3);
    float v0[8], v1[8], v2[8];
    if (st) {  // issue part-0 loads for chunk c+1 early
      stage_load(In, b, c + 1, y0, tid, v0);
      stage_load(In, b, c + 1, y0, tid + 512, v1);
      stage_load(In, b, c + 1, y0, tid + 1024, v2);
    }
    do_taps<0, 4>(cbuf, Wb, c, oc0, row0, l15, k8, acc);
    if (st) {
      stage_write(nbuf, tid, v0);
      stage_write(nbuf, tid + 512, v1);
      stage_write(nbuf, tid + 1024, v2);
      stage_load(In, b, c + 1, y0, tid + 1536, v0);
      stage_load(In, b, c + 1, y0, tid + 2048, v1);
      if (tid < 80) stage_load(In, b, c + 1, y0, tid + 2560, v2);
    }
    do_taps<4, 9>(cbuf, Wb, c, oc0, row0, l15, k8, acc);
    if (st) {
      stage_write(nbuf, tid + 1536, v0);
      stage_write(nbuf, tid + 2048, v1);
      if (tid < 80) stage_write(nbuf, tid + 2560, v2);
    }
    __syncthreads();
  }

  // epilogue: D row = oc (= k8*4 + reg within frag), col = pixel
  #pragma unroll
  for (int mf = 0; mf < 4; ++mf) {
    int ocb = oc0 + mf * 16 + k8 * 4;
    float b0 = Bias[ocb], b1 = Bias[ocb + 1], b2 = Bias[ocb + 2], b3 = Bias[ocb + 3];
    #pragma unroll
    for (int nf = 0; nf < 8; ++nf) {
      int y = y0 + row0 + (nf >> 2);
      int x = (nf & 3) * 16 + l15;
      float* op = Out + ((size_t)(b * 128 + ocb) * 64 + y) * 64 + x;
      op[0]           = acc[mf][nf][0] + b0;
      op[4096]        = acc[mf][nf][1] + b1;
      op[2 * 4096]    = acc[mf][nf][2] + b2;
      op[3 * 4096]    = acc[mf][nf][3] + b3;
    }
  }
}

// ---------------- GroupNorm stats: one block per (b,g), 16ch x 4096 contiguous ----------------
__global__ __launch_bounds__(256) void gn_stats_kernel(const float* __restrict__ X, float* __restrict__ stats) {
  int bg = blockIdx.x;  // b*8+g
  const float* p = X + (size_t)bg * 16 * HW;
  float s = 0.f, sq = 0.f;
  for (int i = threadIdx.x; i < 16 * HW; i += 256) { float v = p[i]; s += v; sq += v * v; }
  __shared__ float ss[256], s2[256];
  ss[threadIdx.x] = s; s2[threadIdx.x] = sq;
  __syncthreads();
  for (int off = 128; off > 0; off >>= 1) {
    if (threadIdx.x < off) { ss[threadIdx.x] += ss[threadIdx.x + off]; s2[threadIdx.x] += s2[threadIdx.x + off]; }
    __syncthreads();
  }
  if (threadIdx.x == 0) {
    const float invn = 1.f / (16.f * HW);
    float mu = ss[0] * invn;
    float var = s2[0] * invn - mu * mu;
    stats[bg * 2] = mu;
    stats[bg * 2 + 1] = rsqrtf(var + 1e-5f);
  }
}

__global__ __launch_bounds__(256) void gn1_silu_kernel(float* __restrict__ A, const float* __restrict__ stats,
                                                       const float* __restrict__ gamma, const float* __restrict__ beta) {
  unsigned idx = blockIdx.x * 256u + threadIdx.x;   // 16777216
  unsigned pc = idx >> 12;
  int c = pc & 127, b = pc >> 7;
  int bg = b * 8 + (c >> 4);
  float mu = stats[bg * 2], ri = stats[bg * 2 + 1];
  float v = A[idx];
  float y = (v - mu) * ri * gamma[c] + beta[c];
  A[idx] = silu_f(y);
}

__global__ __launch_bounds__(256) void gn2_add_silu_kernel(float* __restrict__ S, const float* __restrict__ Xc,
                                                           const float* __restrict__ stats, const float* __restrict__ gamma,
                                                           const float* __restrict__ beta) {
  unsigned idx = blockIdx.x * 256u + threadIdx.x;
  unsigned pc = idx >> 12;
  int c = pc & 127, b = pc >> 7;
  int bg = b * 8 + (c >> 4);
  float mu = stats[bg * 2], ri = stats[bg * 2 + 1];
  float v = Xc[idx];
  float y = (v - mu) * ri * gamma[c] + beta[c];
  float s = S[idx] + y;
  S[idx] = silu_f(s);
}

// ---------------- grid_sample: one block (128 ch) per token ----------------
__global__ __launch_bounds__(128) void gsample_kernel(const float* __restrict__ S2, const float* __restrict__ x,
                                                      float* __restrict__ rd) {
  int token = blockIdx.x;   // B*T
  int c = threadIdx.x;
  int b = token >> 8;
  float cx = x[token * 2], cy = x[token * 2 + 1];
  float fx = (cx + 1.f) * 32.f - 0.5f;   // ((cx+1)*W - 1)*0.5, W=64
  float fy = (cy + 1.f) * 32.f - 0.5f;
  float x0f = floorf(fx), y0f = floorf(fy);
  float wx = fx - x0f, wy = fy - y0f;
  const float* Sb = S2 + ((size_t)b * CSN + c) * HW;
  float acc = 0.f;
  #pragma unroll
  for (int cor = 0; cor < 4; ++cor) {
    float xi = x0f + (float)(cor & 1), yi = y0f + (float)(cor >> 1);
    float wgt = ((cor & 1) ? wx : 1.f - wx) * ((cor >> 1) ? wy : 1.f - wy);
    if (xi >= 0.f && xi <= 63.f && yi >= 0.f && yi <= 63.f)
      acc += Sb[(int)yi * 64 + (int)xi] * wgt;
  }
  rd[(size_t)token * CSN + c] = acc;
}

// ---------------- MLP fc (128->128) with silu; init is per-j bias or per-(b,j) table ----------------
__global__ __launch_bounds__(256) void mlp_fc_kernel(const float* __restrict__ in, const float* __restrict__ w,
                                                     const float* __restrict__ init, int initPerB,
                                                     float* __restrict__ out) {
  int tok0 = blockIdx.x * 2;
  int tid = threadIdx.x;
  __shared__ float sr[2][128];
  sr[tid >> 7][tid & 127] = in[(size_t)tok0 * 128 + tid];
  __syncthreads();
  int t = tid >> 7, j = tid & 127;
  int token = tok0 + t;
  int b = token >> 8;
  float acc = initPerB ? init[b * 128 + j] : init[j];
  #pragma unroll 8
  for (int k = 0; k < 128; ++k) acc += sr[t][k] * w[(size_t)k * 128 + j];
  out[(size_t)token * 128 + j] = silu_f(acc);
}

__global__ __launch_bounds__(256) void mlp3_update_kernel(const float* __restrict__ h2, const float* __restrict__ w3,
                                                          const float* __restrict__ b3, float* __restrict__ x) {
  int token = blockIdx.x * 256 + threadIdx.x;
  if (token >= BN * TN) return;
  float d0 = b3[0], d1 = b3[1];
  const float* h = h2 + (size_t)token * 128;
  #pragma unroll 8
  for (int k = 0; k < 128; ++k) { float hv = h[k]; d0 += hv * w3[k * 2]; d1 += hv * w3[k * 2 + 1]; }
  float nx = x[token * 2] + 0.2f * d0;
  float ny = x[token * 2 + 1] + 0.2f * d1;
  x[token * 2] = fminf(fmaxf(nx, -1.f), 1.f);
  x[token * 2 + 1] = fminf(fmaxf(ny, -1.f), 1.f);
}

extern "C" void kernel_launch(void* const* d_in, const int* in_sizes, int n_in,
                              void* d_out, int out_size, void* d_ws, size_t ws_size,
                              hipStream_t stream) {
  const float* M   = (const float*)d_in[0];
  const float* x0  = (const float*)d_in[1];
  const float* te  = (const float*)d_in[2];
  const float* ipw = (const float*)d_in[3];
  const float* ipb = (const float*)d_in[4];
  const float* c1w = (const float*)d_in[5];
  const float* c1b = (const float*)d_in[6];
  const float* g1w = (const float*)d_in[7];
  const float* g1b = (const float*)d_in[8];
  const float* c2w = (const float*)d_in[9];
  const float* c2b = (const float*)d_in[10];
  const float* g2w = (const float*)d_in[11];
  const float* g2b = (const float*)d_in[12];
  const float* ow  = (const float*)d_in[13];
  const float* ob  = (const float*)d_in[14];
  const float* w1  = (const float*)d_in[15];
  const float* b1  = (const float*)d_in[16];
  const float* w2  = (const float*)d_in[17];
  const float* b2  = (const float*)d_in[18];
  const float* w3  = (const float*)d_in[19];
  const float* b3  = (const float*)d_in[20];

  // workspace layout (floats); ~237 MB + 1.73 MB bf16 weights
  float* ws    = (float*)d_ws;
  float* wx    = ws;                    // 16384 (current x state)
  float* Ms    = wx + 16384;            // 8388608
  float* P     = Ms + 8388608;          // 393216
  float* tctr  = P + 393216;            // 4096
  float* tpart = tctr + 4096;           // 4096
  float* stats = tpart + 4096;          // 512
  float* S     = stats + 512;           // 16777216
  float* A     = S + 16777216;          // 16777216
  float* Bb    = A + 16777216;          // 16777216
  float* rd    = Bb;                    // overlay: Bb free during tail
  float* h1    = Bb + 1048576;
  float* h2    = Bb + 2097152;
  unsigned short* wbuf = (unsigned short*)(Bb + 16777216);  // 6 * 147456 bf16

  copy_kernel<<<64, 256, 0, stream>>>(x0, wx, 16384);
  resize_kernel<<<32768, 256, 0, stream>>>(M, Ms);
  tctr_kernel<<<16, 256, 0, stream>>>(ipw, ipb, te, tctr);
  tpart_kernel<<<16, 256, 0, stream>>>(w1, b1, te, tpart);
  for (int i = 0; i < 3; ++i) {
    wprep_kernel<<<576, 256, 0, stream>>>(c1w + (size_t)i * 147456, wbuf + (size_t)(2 * i) * 147456);
    wprep_kernel<<<576, 256, 0, stream>>>(c2w + (size_t)i * 147456, wbuf + (size_t)(2 * i + 1) * 147456);
  }

  for (int r = 0; r < 3; ++r) {
    raster_kernel<<<dim3(16, 32), 256, 0, stream>>>(wx, P);
    in_proj_kernel<<<dim3(16, 32, 32), 256, 0, stream>>>(Ms, P, ipw, tctr, S);
    for (int i = 0; i < 3; ++i) {
      conv3x3_mfma_kernel<<<dim3(8, 32), 512, 0, stream>>>(S, wbuf + (size_t)(2 * i) * 147456, c1b + i * 128, A);
      gn_stats_kernel<<<256, 256, 0, stream>>>(A, stats);
      gn1_silu_kernel<<<65536, 256, 0, stream>>>(A, stats, g1w + i * 128, g1b + i * 128);
      conv3x3_mfma_kernel<<<dim3(8, 32), 512, 0, stream>>>(A, wbuf + (size_t)(2 * i + 1) * 147456, c2b + i * 128, Bb);
      gn_stats_kernel<<<256, 256, 0, stream>>>(Bb, stats);
      gn2_add_silu_kernel<<<65536, 256, 0, stream>>>(S, Bb, stats, g2w + i * 128, g2b + i * 128);
    }
    out_proj_kernel<<<dim3(16, 32, 32), 256, 0, stream>>>(S, ow, ob, A);
    gsample_kernel<<<8192, 128, 0, stream>>>(A, wx, rd);
    mlp_fc_kernel<<<4096, 256, 0, stream>>>(rd, w1, tpart, 1, h1);
    mlp_fc_kernel<<<4096, 256, 0, stream>>>(h1, w2, b2, 0, h2);
    mlp3_update_kernel<<<32, 256, 0, stream>>>(h2, w3, b3, wx);
  }
  copy_kernel<<<64, 256, 0, stream>>>(wx, (float*)d_out, 16384);
}

// Round 6
// 2695.608 us; speedup vs baseline: 5.3343x; 1.9621x over previous
//
#include <hip/hip_runtime.h>
#include <cstddef>

#define HS 64
#define WS 64
#define BN 32
#define TN 256
#define HW (HS*WS)

typedef __attribute__((ext_vector_type(8))) short bf16x8;
typedef __attribute__((ext_vector_type(4))) float f32x4;

struct __attribute__((aligned(16))) U4 { unsigned x, y, z, w; };

__device__ __forceinline__ float silu_f(float v) { return v / (1.f + __expf(-v)); }

__device__ __forceinline__ unsigned short f2bf(float f) {
  unsigned u = __float_as_uint(f);
  unsigned r = (u + 0x7fffu + ((u >> 16) & 1u)) >> 16;
  return (unsigned short)r;
}
__device__ __forceinline__ float bf2f(unsigned short h) {
  return __uint_as_float((unsigned)h << 16);
}
__device__ __forceinline__ unsigned pack2(float a, float b) {
  return (unsigned)f2bf(a) | ((unsigned)f2bf(b) << 16);
}

__global__ __launch_bounds__(256) void copy_kernel(const float* __restrict__ src, float* __restrict__ dst, int n) {
  int i = blockIdx.x * 256 + threadIdx.x;
  if (i < n) dst[i] = src[i];
}

// ---- resize 128->64 (exact 2x2 avg) + transpose to [b][2cc][4096px][32ch] bf16 ----
__global__ __launch_bounds__(256) void resize_t_kernel(const float* __restrict__ M, unsigned short* __restrict__ Ms4) {
  __shared__ unsigned short lt[4 * 64 * 72];   // [y][x][72 pad]
  int b = blockIdx.y, yt = blockIdx.x;
  int tid = threadIdx.x;
  for (int i = tid; i < 4 * 64 * 64; i += 256) {
    int c = i >> 8, y = (i >> 6) & 3, x = i & 63;
    const float* p = M + (((size_t)(b * 64 + c) * 128) + (yt * 4 + y) * 2) * 128 + 2 * x;
    float2 a = *(const float2*)p;
    float2 bq = *(const float2*)(p + 128);
    lt[(y * 64 + x) * 72 + c] = f2bf(0.25f * (a.x + a.y + bq.x + bq.y));
  }
  __syncthreads();
  for (int i = tid; i < 2048; i += 256) {
    int icq = i & 3, px = (i >> 2) & 255, cc = i >> 10;
    U4 q = *(const U4*)&lt[px * 72 + cc * 32 + icq * 8];
    *(U4*)&Ms4[(((size_t)(b * 2 + cc) * 4096) + yt * 256 + px) * 32 + icq * 8] = q;
  }
}

// ---- conv weight prep: W[oc][ic][3][3] fp32 -> [tap*4+cc][128 oc][32 ic] bf16 ----
__global__ __launch_bounds__(256) void wprep_kernel(const float* __restrict__ Wsrc, unsigned short* __restrict__ Wdst) {
  int idx = blockIdx.x * 256 + threadIdx.x;  // 147456
  if (idx >= 147456) return;
  int icp = idx & 31;
  int oc = (idx >> 5) & 127;
  int tc = idx >> 12;
  int t = tc >> 2, cch = tc & 3;
  Wdst[idx] = f2bf(Wsrc[(size_t)oc * 1152 + (size_t)(cch * 32 + icp) * 9 + t]);
}

// ---- in_proj weight prep: [3 cc][128 oc][32] (cc0/1 = Ms ch, cc2 = P(3)+zeros) ----
__global__ __launch_bounds__(256) void wprep_in_kernel(const float* __restrict__ ipw, unsigned short* __restrict__ wi) {
  int idx = blockIdx.x * 256 + threadIdx.x;  // 12288
  if (idx >= 12288) return;
  int icp = idx & 31, oc = (idx >> 5) & 127, cc = idx >> 12;
  float f = 0.f;
  if (cc < 2) f = ipw[oc * 195 + cc * 32 + icp];
  else if (icp < 3) f = ipw[oc * 195 + 64 + icp];
  wi[idx] = f2bf(f);
}

// ---- out_proj weight prep: [4 cc][128 oc][32] ----
__global__ __launch_bounds__(256) void wprep_out_kernel(const float* __restrict__ ow, unsigned short* __restrict__ wo) {
  int idx = blockIdx.x * 256 + threadIdx.x;  // 16384
  if (idx >= 16384) return;
  int icp = idx & 31, oc = (idx >> 5) & 127, cc = idx >> 12;
  wo[idx] = f2bf(ow[oc * 128 + cc * 32 + icp]);
}

// ---- t-embed -> in_proj per-(b,oc) bias (incl ipb) ----
__global__ __launch_bounds__(256) void tctr_kernel(const float* __restrict__ w, const float* __restrict__ bias,
                                                   const float* __restrict__ te, float* __restrict__ tctr) {
  int i = blockIdx.x * 256 + threadIdx.x;
  if (i >= BN * 128) return;
  int b = i >> 7, o = i & 127;
  float acc = bias[o];
  const float* wp = w + (size_t)o * 195 + 67;
  const float* t = te + b * 128;
  #pragma unroll 8
  for (int k = 0; k < 128; ++k) acc += wp[k] * t[k];
  tctr[i] = acc;
}

// ---- t-embed -> mlp layer1 per-(b,j) bias (incl b1) ----
__global__ __launch_bounds__(256) void tpart_kernel(const float* __restrict__ w1, const float* __restrict__ b1,
                                                    const float* __restrict__ te, float* __restrict__ tp) {
  int i = blockIdx.x * 256 + threadIdx.x;
  if (i >= BN * 128) return;
  int b = i >> 7, j = i & 127;
  float acc = b1[j];
  #pragma unroll 8
  for (int k = 0; k < 128; ++k) acc += te[b * 128 + k] * w1[(size_t)(128 + k) * 128 + j];
  tp[i] = acc;
}

// ---- rasterize -> Pp [b][4096][32] bf16 (ch0=heat,1=vx,2=vy, rest 0) ----
__global__ __launch_bounds__(256) void raster4_kernel(const float* __restrict__ x, unsigned short* __restrict__ Pp) {
  int b = blockIdx.y, blk = blockIdx.x;
  int tid = threadIdx.x;
  int pix = blk * 256 + tid;
  __shared__ float spx[TN], spy[TN];
  __shared__ unsigned short lp[256 * 32];
  spx[tid] = (x[(b * TN + tid) * 2] + 1.f) * 0.5f * (WS - 1);
  spy[tid] = (x[(b * TN + tid) * 2 + 1] + 1.f) * 0.5f * (HS - 1);
  __syncthreads();
  float fx = (float)(pix & 63), fy = (float)(pix >> 6);
  const float coef = -0.5f / (1.44f + 1e-8f);
  float heat = 0.f, sx = 0.f, sy = 0.f, sw = 0.f;
  float prevx = 0.f, prevy = 0.f;
  for (int t = 0; t < TN; ++t) {
    float px = spx[t], py = spy[t];
    float ddx = px - fx, ddy = py - fy;
    float w = __expf(coef * (ddx * ddx + ddy * ddy));
    heat = fmaxf(heat, w);
    float vx = (t == 0) ? 0.f : px - prevx;
    float vy = (t == 0) ? 0.f : py - prevy;
    prevx = px; prevy = py;
    sx += w * vx; sy += w * vy; sw += w;
  }
  float inv = 1.f / fmaxf(sw, 1e-6f);
  U4 q0; q0.x = pack2(heat, sx * inv); q0.y = pack2(sy * inv, 0.f); q0.z = 0u; q0.w = 0u;
  U4 z = {0u, 0u, 0u, 0u};
  *(U4*)&lp[tid * 32 + 0] = q0;
  *(U4*)&lp[tid * 32 + 8] = z;
  *(U4*)&lp[tid * 32 + 16] = z;
  *(U4*)&lp[tid * 32 + 24] = z;
  __syncthreads();
  for (int it = 0; it < 4; ++it) {
    int sid = it * 256 + tid;
    int px = sid >> 2, icq = sid & 3;
    *(U4*)&Pp[((size_t)b * 4096 + blk * 256 + px) * 32 + icq * 8] = *(const U4*)&lp[px * 32 + icq * 8];
  }
}

// ================= MFMA conv machinery (layout [b][cc][4096][32] bf16) =================
// Fragment math (HW-verified r2): A lane: row=oc (l&15), k=(l>>4)*8+j; B lane: k, col=px(l&15);
// D: col=px(l&15), row-offset=(l>>4)*4+reg.

__device__ __forceinline__ U4 stage_fetch(const unsigned short* __restrict__ src, int y0, int sid,
                                          const float* __restrict__ stb, const float* __restrict__ gam,
                                          const float* __restrict__ bet, int cc) {
  int r = sid / 264, t = sid - r * 264;
  int xs = t >> 2, icq = t & 3;
  int y = y0 - 1 + r, x = xs - 1;
  U4 q = {0u, 0u, 0u, 0u};
  if (y >= 0 && y < 64 && x >= 0 && x < 64) {
    q = *(const U4*)&src[((size_t)(y * 64 + x)) * 32 + icq * 8];
    if (stb) {   // fused gn1 affine + silu (only on in-bounds values; padding stays 0)
      int g = cc * 2 + (icq >> 1);
      float mu = stb[g * 2], ri = stb[g * 2 + 1];
      int c0 = cc * 32 + icq * 8;
      unsigned vv[4] = {q.x, q.y, q.z, q.w};
      unsigned oo[4];
      #pragma unroll
      for (int p = 0; p < 4; ++p) {
        float v0 = bf2f((unsigned short)(vv[p] & 0xffffu));
        float v1 = bf2f((unsigned short)(vv[p] >> 16));
        float y0f = (v0 - mu) * ri * gam[c0 + 2 * p] + bet[c0 + 2 * p];
        float y1f = (v1 - mu) * ri * gam[c0 + 2 * p + 1] + bet[c0 + 2 * p + 1];
        oo[p] = pack2(silu_f(y0f), silu_f(y1f));
      }
      q.x = oo[0]; q.y = oo[1]; q.z = oo[2]; q.w = oo[3];
    }
  }
  return q;
}

__device__ __forceinline__ void stage_put(unsigned short* __restrict__ buf, int sid, U4 q) {
  int r = sid / 264, t = sid - r * 264;
  int xs = t >> 2, icq = t & 3;
  *(U4*)&buf[(r * 66 + xs) * 40 + icq * 8] = q;
}

// epilogue shared: acc -> LDS (XOR swz) -> coalesced chunked writes
__device__ __forceinline__ void epilogue_write(unsigned short* __restrict__ lds, f32x4 acc[4][8],
                                               const float* __restrict__ bp, int ocg, int rowg,
                                               int l15, int k8, int tid,
                                               unsigned short* __restrict__ Out4, int b, int px_base) {
  #pragma unroll
  for (int mf = 0; mf < 4; ++mf) {
    int oc = ocg * 64 + mf * 16 + k8 * 4;
    float4 bv = *(const float4*)&bp[oc];
    #pragma unroll
    for (int nf = 0; nf < 8; ++nf) {
      int px = rowg * 128 + nf * 16 + l15;
      unsigned lo = pack2(acc[mf][nf][0] + bv.x, acc[mf][nf][1] + bv.y);
      unsigned hi = pack2(acc[mf][nf][2] + bv.z, acc[mf][nf][3] + bv.w);
      unsigned off = (unsigned)(px * 256 + oc * 2) ^ ((px & 7) << 4);
      *(uint2*)((char*)lds + off) = make_uint2(lo, hi);
    }
  }
  __syncthreads();
  #pragma unroll
  for (int cc = 0; cc < 4; ++cc)
    #pragma unroll
    for (int it = 0; it < 4; ++it) {
      int sid = it * 256 + tid;
      int px = sid >> 2, icq = sid & 3;
      unsigned off = (unsigned)(px * 256 + (cc * 32 + icq * 8) * 2) ^ ((px & 7) << 4);
      U4 q = *(const U4*)((char*)lds + off);
      *(U4*)&Out4[(((size_t)(b * 4 + cc) * 4096) + px_base + px) * 32 + icq * 8] = q;
    }
}

// ---- conv3x3: tile [4y][64x][128oc], 4 waves, dbuf LDS [6][66][40], optional fused gn1+silu ----
__global__ __launch_bounds__(256, 2) void conv3_v2(const unsigned short* __restrict__ In4,
                                                   const unsigned short* __restrict__ Wb,
                                                   const float* __restrict__ Bias,
                                                   const float* __restrict__ st,
                                                   const float* __restrict__ gam,
                                                   const float* __restrict__ bet,
                                                   unsigned short* __restrict__ Out4) {
  __shared__ unsigned short lds[32768];   // 64KB: dbuf 2x15840 during loop; repack [256px][128oc] after
  const int b = blockIdx.y, y0 = blockIdx.x * 4;
  const int tid = threadIdx.x, l = tid & 63, w = tid >> 6;
  const int ocg = w & 1, rowg = w >> 1, l15 = l & 15, k8 = l >> 4;
  const float* stb = st ? st + b * 16 : nullptr;

  f32x4 acc[4][8];
  #pragma unroll
  for (int mf = 0; mf < 4; ++mf)
    #pragma unroll
    for (int nf = 0; nf < 8; ++nf) acc[mf][nf] = (f32x4){0.f, 0.f, 0.f, 0.f};

  const unsigned short* src0 = In4 + ((size_t)(b * 4)) * 4096 * 32;
  #pragma unroll
  for (int i = 0; i < 6; ++i) stage_put(lds, tid + i * 256, stage_fetch(src0, y0, tid + i * 256, stb, gam, bet, 0));
  if (tid < 48) stage_put(lds, 1536 + tid, stage_fetch(src0, y0, 1536 + tid, stb, gam, bet, 0));
  __syncthreads();

  for (int cc = 0; cc < 4; ++cc) {
    const unsigned short* cur = lds + (cc & 1) * 15840;
    unsigned short* nxt = lds + ((cc & 1) ^ 1) * 15840;
    U4 q[7];
    if (cc < 3) {
      const unsigned short* srcn = In4 + ((size_t)(b * 4 + cc + 1)) * 4096 * 32;
      #pragma unroll
      for (int i = 0; i < 6; ++i) q[i] = stage_fetch(srcn, y0, tid + i * 256, stb, gam, bet, cc + 1);
      if (tid < 48) q[6] = stage_fetch(srcn, y0, 1536 + tid, stb, gam, bet, cc + 1);
    }
    #pragma unroll
    for (int t = 0; t < 9; ++t) {
      const int ky = t / 3, kx = t % 3;
      bf16x8 a[4];
      #pragma unroll
      for (int mf = 0; mf < 4; ++mf)
        a[mf] = *(const bf16x8*)&Wb[(((size_t)(t * 4 + cc) * 128) + ocg * 64 + mf * 16 + l15) * 32 + k8 * 8];
      #pragma unroll
      for (int nf = 0; nf < 8; ++nf) {
        int r = rowg * 2 + (nf >> 2) + ky;
        int xs = (nf & 3) * 16 + l15 + kx;
        bf16x8 bv = *(const bf16x8*)&cur[(r * 66 + xs) * 40 + k8 * 8];
        #pragma unroll
        for (int mf = 0; mf < 4; ++mf)
          acc[mf][nf] = __builtin_amdgcn_mfma_f32_16x16x32_bf16(a[mf], bv, acc[mf][nf], 0, 0, 0);
      }
    }
    if (cc < 3) {
      #pragma unroll
      for (int i = 0; i < 6; ++i) stage_put(nxt, tid + i * 256, q[i]);
      if (tid < 48) stage_put(nxt, 1536 + tid, q[6]);
    }
    __syncthreads();
  }
  // note: conv tile px mapping equals rowg*128 + nf*16 + l15 since y=(rowg*2+(nf>>2)), x=(nf&3)*16+l15
  epilogue_write(lds, acc, Bias, ocg, rowg, l15, k8, tid, Out4, b, y0 * 64);
}

// ---- 1x1 conv (in_proj K=3 chunks from 2 tensors / out_proj K=4): direct-global B ----
__global__ __launch_bounds__(256, 2) void conv1_v2(const unsigned short* __restrict__ srcA, int ncA,
                                                   const unsigned short* __restrict__ srcB, int nc,
                                                   const unsigned short* __restrict__ Wb,
                                                   const float* __restrict__ Bias, int perB,
                                                   unsigned short* __restrict__ Out4) {
  __shared__ unsigned short lds[32768];
  const int b = blockIdx.y, px0 = blockIdx.x * 256;
  const int tid = threadIdx.x, l = tid & 63, w = tid >> 6;
  const int ocg = w & 1, rowg = w >> 1, l15 = l & 15, k8 = l >> 4;

  f32x4 acc[4][8];
  #pragma unroll
  for (int mf = 0; mf < 4; ++mf)
    #pragma unroll
    for (int nf = 0; nf < 8; ++nf) acc[mf][nf] = (f32x4){0.f, 0.f, 0.f, 0.f};

  for (int cc = 0; cc < nc; ++cc) {
    const unsigned short* base = (cc < ncA) ? srcA + ((size_t)(b * ncA + cc)) * 4096 * 32
                                            : srcB + ((size_t)b) * 4096 * 32;
    bf16x8 a[4];
    #pragma unroll
    for (int mf = 0; mf < 4; ++mf)
      a[mf] = *(const bf16x8*)&Wb[(((size_t)cc * 128) + ocg * 64 + mf * 16 + l15) * 32 + k8 * 8];
    #pragma unroll
    for (int nf = 0; nf < 8; ++nf) {
      int px = px0 + rowg * 128 + nf * 16 + l15;
      bf16x8 bv = *(const bf16x8*)&base[(size_t)px * 32 + k8 * 8];
      #pragma unroll
      for (int mf = 0; mf < 4; ++mf)
        acc[mf][nf] = __builtin_amdgcn_mfma_f32_16x16x32_bf16(a[mf], bv, acc[mf][nf], 0, 0, 0);
    }
  }
  const float* bp = Bias + (perB ? b * 128 : 0);
  epilogue_write(lds, acc, bp, ocg, rowg, l15, k8, tid, Out4, b, px0);
}

// ---- GN stats: block per (b,cc) -> groups 2cc, 2cc+1 ----
__global__ __launch_bounds__(256) void gnstats4_kernel(const unsigned short* __restrict__ X, float* __restrict__ stats) {
  int bc = blockIdx.x;
  const unsigned short* p = X + (size_t)bc * 4096 * 32;
  float s0 = 0.f, q0 = 0.f, s1 = 0.f, q1 = 0.f;
  for (int px = threadIdx.x; px < 4096; px += 256) {
    const unsigned short* row = p + (size_t)px * 32;
    #pragma unroll
    for (int half = 0; half < 2; ++half) {
      float s = 0.f, qq = 0.f;
      #pragma unroll
      for (int ii = 0; ii < 2; ++ii) {
        U4 v = *(const U4*)&row[half * 16 + ii * 8];
        unsigned a[4] = {v.x, v.y, v.z, v.w};
        #pragma unroll
        for (int p2 = 0; p2 < 4; ++p2) {
          float f0 = bf2f((unsigned short)(a[p2] & 0xffffu));
          float f1 = bf2f((unsigned short)(a[p2] >> 16));
          s += f0 + f1; qq += f0 * f0 + f1 * f1;
        }
      }
      if (half == 0) { s0 += s; q0 += qq; } else { s1 += s; q1 += qq; }
    }
  }
  __shared__ float red[4][256];
  red[0][threadIdx.x] = s0; red[1][threadIdx.x] = q0; red[2][threadIdx.x] = s1; red[3][threadIdx.x] = q1;
  __syncthreads();
  for (int off = 128; off > 0; off >>= 1) {
    if (threadIdx.x < off)
      #pragma unroll
      for (int k = 0; k < 4; ++k) red[k][threadIdx.x] += red[k][threadIdx.x + off];
    __syncthreads();
  }
  if (threadIdx.x == 0) {
    const float invn = 1.f / 65536.f;
    int b = bc >> 2, cc = bc & 3;
    float mu0 = red[0][0] * invn, var0 = red[1][0] * invn - mu0 * mu0;
    float mu1 = red[2][0] * invn, var1 = red[3][0] * invn - mu1 * mu1;
    int g0 = b * 8 + cc * 2;
    stats[g0 * 2] = mu0; stats[g0 * 2 + 1] = rsqrtf(var0 + 1e-5f);
    stats[(g0 + 1) * 2] = mu1; stats[(g0 + 1) * 2 + 1] = rsqrtf(var1 + 1e-5f);
  }
}

// ---- S = silu(S + gn2(Bb)) elementwise on [b][cc][px][32] bf16 ----
__global__ __launch_bounds__(256) void gn2add4_kernel(unsigned short* __restrict__ S, const unsigned short* __restrict__ Bb,
                                                      const float* __restrict__ stats, const float* __restrict__ gam,
                                                      const float* __restrict__ bet) {
  size_t e8 = (size_t)blockIdx.x * 256 + threadIdx.x;   // 2,097,152
  size_t e = e8 * 8;
  int ch = (int)(e & 31);
  int cc = (int)((e >> 17) & 3);
  int b = (int)(e >> 19);
  int g = cc * 2 + (ch >> 4);
  float mu = stats[(b * 8 + g) * 2], ri = stats[(b * 8 + g) * 2 + 1];
  int c0 = cc * 32 + ch;
  float4 g0 = *(const float4*)&gam[c0], g1 = *(const float4*)&gam[c0 + 4];
  float4 b0 = *(const float4*)&bet[c0], b1 = *(const float4*)&bet[c0 + 4];
  float gv[8] = {g0.x, g0.y, g0.z, g0.w, g1.x, g1.y, g1.z, g1.w};
  float bv[8] = {b0.x, b0.y, b0.z, b0.w, b1.x, b1.y, b1.z, b1.w};
  U4 vb = *(const U4*)&Bb[e];
  U4 vs = *(const U4*)&S[e];
  unsigned ab[4] = {vb.x, vb.y, vb.z, vb.w};
  unsigned as[4] = {vs.x, vs.y, vs.z, vs.w};
  unsigned out[4];
  #pragma unroll
  for (int p = 0; p < 4; ++p) {
    float h0 = (bf2f((unsigned short)(ab[p] & 0xffffu)) - mu) * ri * gv[2 * p] + bv[2 * p];
    float h1 = (bf2f((unsigned short)(ab[p] >> 16)) - mu) * ri * gv[2 * p + 1] + bv[2 * p + 1];
    float r0 = silu_f(bf2f((unsigned short)(as[p] & 0xffffu)) + h0);
    float r1 = silu_f(bf2f((unsigned short)(as[p] >> 16)) + h1);
    out[p] = pack2(r0, r1);
  }
  U4 q; q.x = out[0]; q.y = out[1]; q.z = out[2]; q.w = out[3];
  *(U4*)&S[e] = q;
}

// ---- grid_sample from [b][cc][px][32] bf16 ----
__global__ __launch_bounds__(128) void gsample4_kernel(const unsigned short* __restrict__ S2, const float* __restrict__ x,
                                                       float* __restrict__ rd) {
  int token = blockIdx.x, c = threadIdx.x, b = token >> 8;
  float cx = x[token * 2], cy = x[token * 2 + 1];
  float fx = (cx + 1.f) * 32.f - 0.5f;
  float fy = (cy + 1.f) * 32.f - 0.5f;
  float x0f = floorf(fx), y0f = floorf(fy);
  float wx = fx - x0f, wy = fy - y0f;
  const unsigned short* Sb = S2 + ((size_t)(b * 4 + (c >> 5)) * 4096) * 32 + (c & 31);
  float acc = 0.f;
  #pragma unroll
  for (int cor = 0; cor < 4; ++cor) {
    float xi = x0f + (float)(cor & 1), yi = y0f + (float)(cor >> 1);
    float wgt = ((cor & 1) ? wx : 1.f - wx) * ((cor >> 1) ? wy : 1.f - wy);
    if (xi >= 0.f && xi <= 63.f && yi >= 0.f && yi <= 63.f)
      acc += bf2f(Sb[(size_t)((int)yi * 64 + (int)xi) * 32]) * wgt;
  }
  rd[(size_t)token * 128 + c] = acc;
}

// ---- MLP fc 128->128 + silu ----
__global__ __launch_bounds__(256) void mlp_fc_kernel(const float* __restrict__ in, const float* __restrict__ w,
                                                     const float* __restrict__ init, int initPerB,
                                                     float* __restrict__ out) {
  int tok0 = blockIdx.x * 2;
  int tid = threadIdx.x;
  __shared__ float sr[2][128];
  sr[tid >> 7][tid & 127] = in[(size_t)tok0 * 128 + tid];
  __syncthreads();
  int t = tid >> 7, j = tid & 127;
  int token = tok0 + t;
  int b = token >> 8;
  float acc = initPerB ? init[b * 128 + j] : init[j];
  #pragma unroll 8
  for (int k = 0; k < 128; ++k) acc += sr[t][k] * w[(size_t)k * 128 + j];
  out[(size_t)token * 128 + j] = silu_f(acc);
}

__global__ __launch_bounds__(256) void mlp3_update_kernel(const float* __restrict__ h2, const float* __restrict__ w3,
                                                          const float* __restrict__ b3, float* __restrict__ x) {
  int token = blockIdx.x * 256 + threadIdx.x;
  if (token >= BN * TN) return;
  float d0 = b3[0], d1 = b3[1];
  const float* h = h2 + (size_t)token * 128;
  #pragma unroll 8
  for (int k = 0; k < 128; ++k) { float hv = h[k]; d0 += hv * w3[k * 2]; d1 += hv * w3[k * 2 + 1]; }
  float nx = x[token * 2] + 0.2f * d0;
  float ny = x[token * 2 + 1] + 0.2f * d1;
  x[token * 2] = fminf(fmaxf(nx, -1.f), 1.f);
  x[token * 2 + 1] = fminf(fmaxf(ny, -1.f), 1.f);
}

extern "C" void kernel_launch(void* const* d_in, const int* in_sizes, int n_in,
                              void* d_out, int out_size, void* d_ws, size_t ws_size,
                              hipStream_t stream) {
  const float* M   = (const float*)d_in[0];
  const float* x0  = (const float*)d_in[1];
  const float* te  = (const float*)d_in[2];
  const float* ipw = (const float*)d_in[3];
  const float* ipb = (const float*)d_in[4];
  const float* c1w = (const float*)d_in[5];
  const float* c1b = (const float*)d_in[6];
  const float* g1w = (const float*)d_in[7];
  const float* g1b = (const float*)d_in[8];
  const float* c2w = (const float*)d_in[9];
  const float* c2b = (const float*)d_in[10];
  const float* g2w = (const float*)d_in[11];
  const float* g2b = (const float*)d_in[12];
  const float* ow  = (const float*)d_in[13];
  const float* ob  = (const float*)d_in[14];
  const float* w1  = (const float*)d_in[15];
  const float* b1  = (const float*)d_in[16];
  const float* w2  = (const float*)d_in[17];
  const float* b2  = (const float*)d_in[18];
  const float* w3  = (const float*)d_in[19];
  const float* b3  = (const float*)d_in[20];

  // ---- workspace layout ----
  float* f     = (float*)d_ws;
  float* wx    = f;                      // 16384
  float* tctr  = wx + 16384;             // 4096
  float* tpart = tctr + 4096;            // 4096
  float* st1   = tpart + 4096;           // 512
  float* st2   = st1 + 512;              // 512
  float* rd    = st2 + 512;              // 1048576
  float* h1    = rd + 1048576;           // 1048576
  float* h2    = h1 + 1048576;           // 1048576
  unsigned short* u0 = (unsigned short*)(h2 + 1048576);
  unsigned short* Ms4 = u0;              // 32*2*4096*32 = 8388608
  unsigned short* Pp  = Ms4 + 8388608;   // 32*4096*32 = 4194304
  unsigned short* S4  = Pp + 4194304;    // 16777216
  unsigned short* A4  = S4 + 16777216;   // 16777216
  unsigned short* B4  = A4 + 16777216;   // 16777216
  unsigned short* wc  = B4 + 16777216;   // 6*147456
  unsigned short* wi  = wc + 884736;     // 12288
  unsigned short* wo  = wi + 12288;      // 16384

  copy_kernel<<<64, 256, 0, stream>>>(x0, wx, 16384);
  resize_t_kernel<<<dim3(16, 32), 256, 0, stream>>>(M, Ms4);
  tctr_kernel<<<16, 256, 0, stream>>>(ipw, ipb, te, tctr);
  tpart_kernel<<<16, 256, 0, stream>>>(w1, b1, te, tpart);
  for (int i = 0; i < 3; ++i) {
    wprep_kernel<<<576, 256, 0, stream>>>(c1w + (size_t)i * 147456, wc + (size_t)(2 * i) * 147456);
    wprep_kernel<<<576, 256, 0, stream>>>(c2w + (size_t)i * 147456, wc + (size_t)(2 * i + 1) * 147456);
  }
  wprep_in_kernel<<<48, 256, 0, stream>>>(ipw, wi);
  wprep_out_kernel<<<64, 256, 0, stream>>>(ow, wo);

  for (int r = 0; r < 3; ++r) {
    raster4_kernel<<<dim3(16, 32), 256, 0, stream>>>(wx, Pp);
    conv1_v2<<<dim3(16, 32), 256, 0, stream>>>(Ms4, 2, Pp, 3, wi, tctr, 1, S4);
    for (int i = 0; i < 3; ++i) {
      conv3_v2<<<dim3(16, 32), 256, 0, stream>>>(S4, wc + (size_t)(2 * i) * 147456, c1b + i * 128,
                                                 nullptr, nullptr, nullptr, A4);
      gnstats4_kernel<<<128, 256, 0, stream>>>(A4, st1);
      conv3_v2<<<dim3(16, 32), 256, 0, stream>>>(A4, wc + (size_t)(2 * i + 1) * 147456, c2b + i * 128,
                                                 st1, g1w + i * 128, g1b + i * 128, B4);
      gnstats4_kernel<<<128, 256, 0, stream>>>(B4, st2);
      gn2add4_kernel<<<8192, 256, 0, stream>>>(S4, B4, st2, g2w + i * 128, g2b + i * 128);
    }
    conv1_v2<<<dim3(16, 32), 256, 0, stream>>>(S4, 4, nullptr, 4, wo, ob, 0, A4);
    gsample4_kernel<<<8192, 128, 0, stream>>>(A4, wx, rd);
    mlp_fc_kernel<<<4096, 256, 0, stream>>>(rd, w1, tpart, 1, h1);
    mlp_fc_kernel<<<4096, 256, 0, stream>>>(h1, w2, b2, 0, h2);
    mlp3_update_kernel<<<32, 256, 0, stream>>>(h2, w3, b3, wx);
  }
  copy_kernel<<<64, 256, 0, stream>>>(wx, (float*)d_out, 16384);
}